// Round 1
// baseline (75.210 us; speedup 1.0000x reference)
//
#include <hip/hip_runtime.h>
#include <math.h>

// LinearAttention: L=4096, B=4, H=8, D=Dv=64, fp32.
// out[l,b,h,e] = (phiQ[l,bh,:] . kv[bh,:,e]) / (phiQ[l,bh,:] . ksum[bh,:] + eps)
// kv[bh,d,e] = sum_l phiK[l,bh,d] * V[l,bh,e]   (GLOBAL sum, not causal)
// phi(x) = elu(x)+1 = x>0 ? x+1 : exp(x)

#define L_TOT 4096
#define B_    4
#define H_    8
#define D_    64
#define NBH   32            // B*H
#define ROWSTRIDE 2048      // B*H*D floats between consecutive l
#define KVSZ  4160          // 64*64 kv + 64 ksum
#define EPS_  1e-6f

__device__ __forceinline__ float phi_(float x) {
    return x > 0.0f ? x + 1.0f : __expf(x);
}

// ---------------- Pass 1: partial kv + ksum per (chunk, bh) ----------------
// grid = (nchunk, 32), block = 256. Each thread owns a 4x4 tile of kv[64][64].
__global__ __launch_bounds__(256) void kv_partial_kernel(
    const float* __restrict__ K, const float* __restrict__ V,
    float* __restrict__ part, int Lc)
{
    __shared__ float ph[8][64];
    __shared__ float vv[8][64];

    const int tid = threadIdx.x;
    const int c   = blockIdx.x;
    const int bh  = blockIdx.y;
    const int l0c  = c * Lc;
    const int lend = min(l0c + Lc, L_TOT);

    const int td = tid >> 4;        // 0..15 -> d-tile
    const int te = tid & 15;        // 0..15 -> e-tile
    const int lr = tid >> 5;        // 0..7  staging row
    const int lc = (tid & 31) * 2;  // staging col (float2)

    float acc[4][4] = {{0.f}};
    float ks[4] = {0.f, 0.f, 0.f, 0.f};

    const size_t bh_off = (size_t)bh * D_;

    for (int l0 = l0c; l0 < lend; l0 += 8) {
        const int l = l0 + lr;
        const bool ok = (l < lend);
        float2 kk = make_float2(0.f, 0.f);
        float2 vx = make_float2(0.f, 0.f);
        if (ok) {
            const size_t base = (size_t)l * ROWSTRIDE + bh_off + lc;
            kk = *(const float2*)(K + base);
            vx = *(const float2*)(V + base);
        }
        __syncthreads();   // previous iteration's LDS reads done
        // NOTE: phi(0)=1, so out-of-range rows must store literal 0
        ph[lr][lc]     = ok ? phi_(kk.x) : 0.f;
        ph[lr][lc + 1] = ok ? phi_(kk.y) : 0.f;
        vv[lr][lc]     = vx.x;
        vv[lr][lc + 1] = vx.y;
        __syncthreads();

        #pragma unroll
        for (int r = 0; r < 8; ++r) {
            float4 pa = *(const float4*)&ph[r][td * 4];
            float4 vb = *(const float4*)&vv[r][te * 4];
            float pav[4] = {pa.x, pa.y, pa.z, pa.w};
            float vbv[4] = {vb.x, vb.y, vb.z, vb.w};
            #pragma unroll
            for (int i = 0; i < 4; ++i) {
                ks[i] += pav[i];
                #pragma unroll
                for (int j = 0; j < 4; ++j)
                    acc[i][j] = fmaf(pav[i], vbv[j], acc[i][j]);
            }
        }
    }

    float* pb = part + ((size_t)c * NBH + bh) * KVSZ;
    #pragma unroll
    for (int i = 0; i < 4; ++i) {
        float4 o = make_float4(acc[i][0], acc[i][1], acc[i][2], acc[i][3]);
        *(float4*)&pb[(td * 4 + i) * 64 + te * 4] = o;
    }
    if (te == 0) {
        #pragma unroll
        for (int i = 0; i < 4; ++i) pb[4096 + td * 4 + i] = ks[i];
    }
}

// ---------------- Pass 1b: reduce partials ----------------
__global__ __launch_bounds__(256) void kv_reduce_kernel(
    const float* __restrict__ part, float* __restrict__ fin, int nchunk)
{
    const int idx = blockIdx.x * 256 + threadIdx.x;
    if (idx >= NBH * KVSZ) return;
    float s = 0.f;
    for (int c = 0; c < nchunk; ++c)
        s += part[(size_t)c * (NBH * KVSZ) + idx];
    fin[idx] = s;
}

// ---------------- Pass 2: per-token output ----------------
// grid = 1024 (32 bh x 32 l-chunks of 128), block = 256 (4 waves).
// Lane e caches kv[:,e] in 64 VGPRs; per token: phiQ broadcast via LDS,
// den via 6-step butterfly shuffle.
__global__ __launch_bounds__(256) void attn_out_kernel(
    const float* __restrict__ Q, const float* __restrict__ fin,
    float* __restrict__ out)
{
    __shared__ float pq[4][64];

    const int tid  = threadIdx.x;
    const int lane = tid & 63;
    const int w    = tid >> 6;
    const int bid  = blockIdx.x;
    const int bh   = bid & 31;
    const int chunk = bid >> 5;     // 0..31, 128 tokens each

    const float* fb = fin + (size_t)bh * KVSZ;
    float4 kvc[16];
    #pragma unroll
    for (int d4 = 0; d4 < 16; ++d4) {
        kvc[d4].x = fb[(d4 * 4 + 0) * 64 + lane];
        kvc[d4].y = fb[(d4 * 4 + 1) * 64 + lane];
        kvc[d4].z = fb[(d4 * 4 + 2) * 64 + lane];
        kvc[d4].w = fb[(d4 * 4 + 3) * 64 + lane];
    }
    const float ksl = fb[4096 + lane];

    const int lbeg = chunk * 128 + w;
    const int lfin = chunk * 128 + 128;
    for (int l = lbeg; l < lfin; l += 4) {
        const size_t base = (size_t)l * ROWSTRIDE + (size_t)bh * 64;
        const float p = phi_(Q[base + lane]);

        // denominator: wave-wide reduce of p * ksum[lane]
        float den = p * ksl;
        #pragma unroll
        for (int m = 32; m >= 1; m >>= 1)
            den += __shfl_xor(den, m, 64);

        // broadcast phiQ row to all lanes via LDS (wave-coherent)
        pq[w][lane] = p;
        __builtin_amdgcn_wave_barrier();

        float n0 = 0.f, n1 = 0.f, n2 = 0.f, n3 = 0.f;
        #pragma unroll
        for (int d4 = 0; d4 < 16; ++d4) {
            float4 pv = *(const float4*)&pq[w][d4 * 4];
            n0 = fmaf(pv.x, kvc[d4].x, n0);
            n1 = fmaf(pv.y, kvc[d4].y, n1);
            n2 = fmaf(pv.z, kvc[d4].z, n2);
            n3 = fmaf(pv.w, kvc[d4].w, n3);
        }
        const float num = (n0 + n1) + (n2 + n3);
        out[base + lane] = num / (den + EPS_);
        __builtin_amdgcn_wave_barrier();   // keep reads before next overwrite
    }
}

extern "C" void kernel_launch(void* const* d_in, const int* in_sizes, int n_in,
                              void* d_out, int out_size, void* d_ws, size_t ws_size,
                              hipStream_t stream) {
    const float* Q = (const float*)d_in[0];
    const float* K = (const float*)d_in[1];
    const float* V = (const float*)d_in[2];
    float* outp = (float*)d_out;
    float* ws   = (float*)d_ws;

    const size_t slab = (size_t)NBH * KVSZ;          // 133120 floats = 532 KB
    const size_t cap  = ws_size / (slab * sizeof(float));

    int nchunk;
    float* fin = ws;
    float* part;
    bool do_reduce;
    if (cap >= 3) {                 // final slab + >=2 partial slabs
        size_t n = cap - 1;
        if (n > 16) n = 16;
        nchunk = (int)n;
        part = ws + slab;
        do_reduce = true;
    } else {                        // tiny ws: single chunk, write final directly
        nchunk = 1;
        part = ws;
        do_reduce = false;
    }
    const int Lc = (L_TOT + nchunk - 1) / nchunk;

    hipLaunchKernelGGL(kv_partial_kernel, dim3(nchunk, NBH), dim3(256), 0, stream,
                       K, V, part, Lc);
    if (do_reduce) {
        const int nb = (NBH * KVSZ + 255) / 256;
        hipLaunchKernelGGL(kv_reduce_kernel, dim3(nb), dim3(256), 0, stream,
                           part, fin, nchunk);
    }
    hipLaunchKernelGGL(attn_out_kernel, dim3(1024), dim3(256), 0, stream,
                       Q, fin, outp);
}

// Round 2
// 71.437 us; speedup vs baseline: 1.0528x; 1.0528x over previous
//
#include <hip/hip_runtime.h>
#include <math.h>

// LinearAttention: L=4096, B=4, H=8, D=Dv=64, fp32.
// out[l,b,h,e] = (phiQ[l,bh,:] . kv[bh,:,e]) / (phiQ[l,bh,:] . ksum[bh,:] + eps)
// kv[bh,d,e] = sum_l phiK[l,bh,d] * V[l,bh,e]   (GLOBAL sum, not causal)
// phi(x) = elu(x)+1 = x>0 ? x+1 : exp(x)

#define L_TOT 4096
#define NBH   32            // B*H
#define ROWSTRIDE 2048      // B*H*D floats between consecutive l
#define KVSZ  4160          // 64*64 kv + 64 ksum
#define EPS_  1e-6f

__device__ __forceinline__ float phi_(float x) {
    return x > 0.0f ? x + 1.0f : __expf(x);
}

// ---------------- Pass 1: partial kv + ksum per (chunk, bh) ----------------
// grid = (nchunk, 32), block = 256. Each thread owns a 4x4 tile of kv[64][64].
// 16 rows staged per barrier round, next round's globals prefetched across
// the compute to hide HBM latency.
__global__ __launch_bounds__(256) void kv_partial_kernel(
    const float* __restrict__ K, const float* __restrict__ V,
    float* __restrict__ part, int Lc)
{
    __shared__ float ph[16][64];
    __shared__ float vv[16][64];

    const int tid = threadIdx.x;
    const int c   = blockIdx.x;
    const int bh  = blockIdx.y;
    const int l0c  = c * Lc;
    const int lend = min(l0c + Lc, L_TOT);

    const int td = tid >> 4;        // 0..15 -> d-tile (thread's 4 rows)
    const int te = tid & 15;        // 0..15 -> e-tile (thread's 4 cols)
    const int lr = tid >> 4;        // 0..15  staging row
    const int lc = (tid & 15) * 4;  // staging col (float4)

    float acc[4][4] = {{0.f}};
    float ks[4] = {0.f, 0.f, 0.f, 0.f};

    const size_t bh_off = (size_t)bh * 64;

    // prologue prefetch (round 0)
    float4 kk = make_float4(0.f, 0.f, 0.f, 0.f);
    float4 vx = make_float4(0.f, 0.f, 0.f, 0.f);
    bool ok = (l0c + lr) < lend;
    if (ok) {
        const size_t base = (size_t)(l0c + lr) * ROWSTRIDE + bh_off + lc;
        kk = *(const float4*)(K + base);
        vx = *(const float4*)(V + base);
    }

    for (int l0 = l0c; l0 < lend; l0 += 16) {
        float4 pk;
        pk.x = ok ? phi_(kk.x) : 0.f;   // phi(0)=1, so invalid rows store 0
        pk.y = ok ? phi_(kk.y) : 0.f;
        pk.z = ok ? phi_(kk.z) : 0.f;
        pk.w = ok ? phi_(kk.w) : 0.f;
        __syncthreads();                 // previous round's LDS reads done
        *(float4*)&ph[lr][lc] = pk;
        *(float4*)&vv[lr][lc] = vx;      // vx is 0 when !ok
        __syncthreads();

        // prefetch next round while computing this one
        const int ln = l0 + 16 + lr;
        ok = (ln < lend);
        kk = make_float4(0.f, 0.f, 0.f, 0.f);
        vx = make_float4(0.f, 0.f, 0.f, 0.f);
        if (ok) {
            const size_t base = (size_t)ln * ROWSTRIDE + bh_off + lc;
            kk = *(const float4*)(K + base);
            vx = *(const float4*)(V + base);
        }

        #pragma unroll
        for (int r = 0; r < 16; ++r) {
            float4 pa = *(const float4*)&ph[r][td * 4];
            float4 vb = *(const float4*)&vv[r][te * 4];
            float pav[4] = {pa.x, pa.y, pa.z, pa.w};
            float vbv[4] = {vb.x, vb.y, vb.z, vb.w};
            #pragma unroll
            for (int i = 0; i < 4; ++i) {
                ks[i] += pav[i];
                #pragma unroll
                for (int j = 0; j < 4; ++j)
                    acc[i][j] = fmaf(pav[i], vbv[j], acc[i][j]);
            }
        }
    }

    float* pb = part + ((size_t)c * NBH + bh) * KVSZ;
    #pragma unroll
    for (int i = 0; i < 4; ++i) {
        float4 o = make_float4(acc[i][0], acc[i][1], acc[i][2], acc[i][3]);
        *(float4*)&pb[(td * 4 + i) * 64 + te * 4] = o;
    }
    if (te == 0) {
        #pragma unroll
        for (int i = 0; i < 4; ++i) pb[4096 + td * 4 + i] = ks[i];
    }
}

// ---------------- Pass 1b: reduce partials ----------------
__global__ __launch_bounds__(256) void kv_reduce_kernel(
    const float* __restrict__ part, float* __restrict__ fin, int nchunk)
{
    const int idx = blockIdx.x * 256 + threadIdx.x;
    if (idx >= NBH * KVSZ) return;
    float s = 0.f;
    for (int c = 0; c < nchunk; ++c)
        s += part[(size_t)c * (NBH * KVSZ) + idx];
    fin[idx] = s;
}

// ---------------- Pass 2: per-token output ----------------
// grid = 1024 (32 bh x 32 l-chunks of 128), block = 256 (4 waves).
// Lane e caches kv[:,e] in 64 VGPRs (launch_bounds(256,4) -> 128 VGPR cap
// forces residency). Each wave-iteration handles 4 tokens: float4 Q loads
// (lane -> tok=lane>>4, cols (lane&15)*4), next group's Q prefetched, 4
// interleaved butterfly reductions for the denominators.
__global__ __launch_bounds__(256, 4) void attn_out_kernel(
    const float* __restrict__ Q, const float* __restrict__ fin,
    float* __restrict__ out)
{
    __shared__ float pq[4][4][64];   // [wave][tok][d]

    const int tid  = threadIdx.x;
    const int lane = tid & 63;
    const int w    = tid >> 6;
    const int bh   = blockIdx.x & 31;
    const int chunk = blockIdx.x >> 5;     // 0..31, 128 tokens each

    const float* fb = fin + (size_t)bh * KVSZ;
    float kvc[64];
    #pragma unroll
    for (int d = 0; d < 64; ++d) kvc[d] = fb[d * 64 + lane];
    const float ksl = fb[4096 + lane];

    const int tsub = lane >> 4;        // token-in-group 0..3
    const int col  = (lane & 15) * 4;  // d-columns this lane stages

    const int lbeg = chunk * 128 + w * 4;   // first token of group 0
    size_t qbase = (size_t)(lbeg + tsub) * ROWSTRIDE + (size_t)bh * 64 + col;

    float4 qv = *(const float4*)(Q + qbase);

    #pragma unroll
    for (int i = 0; i < 8; ++i) {
        float4 qn;
        if (i < 7) qn = *(const float4*)(Q + qbase + (size_t)16 * ROWSTRIDE);

        float4 pk;
        pk.x = phi_(qv.x); pk.y = phi_(qv.y);
        pk.z = phi_(qv.z); pk.w = phi_(qv.w);
        *(float4*)&pq[w][tsub][col] = pk;
        __builtin_amdgcn_wave_barrier();

        // numerators: 4 independent token chains against the resident column
        float n0 = 0.f, n1 = 0.f, n2 = 0.f, n3 = 0.f;
        #pragma unroll
        for (int d4 = 0; d4 < 16; ++d4) {
            float4 p0 = *(const float4*)&pq[w][0][d4 * 4];
            float4 p1 = *(const float4*)&pq[w][1][d4 * 4];
            float4 p2 = *(const float4*)&pq[w][2][d4 * 4];
            float4 p3 = *(const float4*)&pq[w][3][d4 * 4];
            const float c0 = kvc[d4 * 4 + 0], c1 = kvc[d4 * 4 + 1];
            const float c2 = kvc[d4 * 4 + 2], c3 = kvc[d4 * 4 + 3];
            n0 = fmaf(p0.x, c0, n0); n0 = fmaf(p0.y, c1, n0);
            n0 = fmaf(p0.z, c2, n0); n0 = fmaf(p0.w, c3, n0);
            n1 = fmaf(p1.x, c0, n1); n1 = fmaf(p1.y, c1, n1);
            n1 = fmaf(p1.z, c2, n1); n1 = fmaf(p1.w, c3, n1);
            n2 = fmaf(p2.x, c0, n2); n2 = fmaf(p2.y, c1, n2);
            n2 = fmaf(p2.z, c2, n2); n2 = fmaf(p2.w, c3, n2);
            n3 = fmaf(p3.x, c0, n3); n3 = fmaf(p3.y, c1, n3);
            n3 = fmaf(p3.z, c2, n3); n3 = fmaf(p3.w, c3, n3);
        }

        // denominators: 4 interleaved 6-step butterflies
        float d0 = pq[w][0][lane] * ksl;
        float d1 = pq[w][1][lane] * ksl;
        float d2 = pq[w][2][lane] * ksl;
        float d3 = pq[w][3][lane] * ksl;
        #pragma unroll
        for (int m = 32; m >= 1; m >>= 1) {
            d0 += __shfl_xor(d0, m, 64);
            d1 += __shfl_xor(d1, m, 64);
            d2 += __shfl_xor(d2, m, 64);
            d3 += __shfl_xor(d3, m, 64);
        }

        const int l0g = lbeg + i * 16;
        const size_t obase = (size_t)l0g * ROWSTRIDE + (size_t)bh * 64 + lane;
        out[obase]                 = n0 / (d0 + EPS_);
        out[obase + 1 * ROWSTRIDE] = n1 / (d1 + EPS_);
        out[obase + 2 * ROWSTRIDE] = n2 / (d2 + EPS_);
        out[obase + 3 * ROWSTRIDE] = n3 / (d3 + EPS_);

        __builtin_amdgcn_wave_barrier();   // pq reads done before next overwrite
        qv = qn;
        qbase += (size_t)16 * ROWSTRIDE;
    }
}

extern "C" void kernel_launch(void* const* d_in, const int* in_sizes, int n_in,
                              void* d_out, int out_size, void* d_ws, size_t ws_size,
                              hipStream_t stream) {
    const float* Q = (const float*)d_in[0];
    const float* K = (const float*)d_in[1];
    const float* V = (const float*)d_in[2];
    float* outp = (float*)d_out;
    float* ws   = (float*)d_ws;

    const size_t slab = (size_t)NBH * KVSZ;          // 133120 floats = 532 KB
    const size_t cap  = ws_size / (slab * sizeof(float));

    int nchunk;
    float* fin = ws;
    float* part;
    bool do_reduce;
    if (cap >= 3) {                 // final slab + >=2 partial slabs
        size_t n = cap - 1;
        if (n > 32) n = 32;
        nchunk = (int)n;
        part = ws + slab;
        do_reduce = true;
    } else {                        // tiny ws: single chunk, write final directly
        nchunk = 1;
        part = ws;
        do_reduce = false;
    }
    const int Lc = (L_TOT + nchunk - 1) / nchunk;

    hipLaunchKernelGGL(kv_partial_kernel, dim3(nchunk, NBH), dim3(256), 0, stream,
                       K, V, part, Lc);
    if (do_reduce) {
        const int nb = (NBH * KVSZ + 255) / 256;
        hipLaunchKernelGGL(kv_reduce_kernel, dim3(nb), dim3(256), 0, stream,
                           part, fin, nchunk);
    }
    hipLaunchKernelGGL(attn_out_kernel, dim3(1024), dim3(256), 0, stream,
                       Q, fin, outp);
}

// Round 3
// 68.053 us; speedup vs baseline: 1.1052x; 1.0497x over previous
//
#include <hip/hip_runtime.h>
#include <math.h>

// LinearAttention: L=4096, B=4, H=8, D=Dv=64, fp32.
// out[l,b,h,e] = (phiQ[l,bh,:] . kv[bh,:,e]) / (phiQ[l,bh,:] . ksum[bh,:] + eps)
// kv[bh,d,e] = sum_l phiK[l,bh,d] * V[l,bh,e]   (GLOBAL sum, not causal)
// phi(x) = elu(x)+1 = x>0 ? x+1 : exp(x)

#define L_TOT 4096
#define NBH   32            // B*H
#define ROWSTRIDE 2048      // B*H*D floats between consecutive l
#define KVSZ  4160          // 64*64 kv + 64 ksum
#define EPS_  1e-6f

__device__ __forceinline__ float phi_(float x) {
    return x > 0.0f ? x + 1.0f : __expf(x);
}

// ---------------- Pass 1: partial kv + ksum per (chunk, bh) ----------------
// grid = (nchunk, 32), block = 256 (4 waves). Each WAVE owns a full 64x64 kv
// accumulator (8x8 tile per lane = 64 VGPRs) and processes a disjoint 8-row
// slice of each 32-row staged tile -> only 4 ds_read_b128 per row per wave
// (16 FMAs per b128). Waves block-reduce through LDS at the end.
__global__ __launch_bounds__(256) void kv_partial_kernel(
    const float* __restrict__ K, const float* __restrict__ V,
    float* __restrict__ part, int Lc)
{
    __shared__ float sm[12480];                    // 48.75 KB
    float (*phk)[64] = (float(*)[64])sm;           // [32][64] staged phiK
    float (*vvv)[64] = (float(*)[64])(sm + 2048);  // [32][64] staged V

    const int tid  = threadIdx.x;
    const int w    = tid >> 6;          // wave 0..3
    const int lane = tid & 63;
    const int c    = blockIdx.x;
    const int bh   = blockIdx.y;
    const int l0c  = c * Lc;
    const int lend = min(l0c + Lc, L_TOT);

    const int d0 = (lane >> 3) * 8;     // lane's 8 kv-rows (d)
    const int e0 = (lane & 7) * 8;      // lane's 8 kv-cols (e)

    const int sr = tid >> 4;            // staging row 0..15 (and +16)
    const int sc = (tid & 15) * 4;      // staging col (float4)

    float acc[8][8];
    #pragma unroll
    for (int i = 0; i < 8; ++i)
        #pragma unroll
        for (int j = 0; j < 8; ++j) acc[i][j] = 0.f;
    float ks[8] = {0.f,0.f,0.f,0.f,0.f,0.f,0.f,0.f};

    const size_t bh_off = (size_t)bh * 64;

    // prologue prefetch (rows l0c+sr, l0c+sr+16)
    float4 z4 = make_float4(0.f, 0.f, 0.f, 0.f);
    bool ok0 = (l0c + sr) < lend;
    bool ok1 = (l0c + sr + 16) < lend;
    float4 ka = z4, kb = z4, va = z4, vb = z4;
    if (ok0) {
        const size_t b = (size_t)(l0c + sr) * ROWSTRIDE + bh_off + sc;
        ka = *(const float4*)(K + b);  va = *(const float4*)(V + b);
    }
    if (ok1) {
        const size_t b = (size_t)(l0c + sr + 16) * ROWSTRIDE + bh_off + sc;
        kb = *(const float4*)(K + b);  vb = *(const float4*)(V + b);
    }

    for (int l0 = l0c; l0 < lend; l0 += 32) {
        float4 pa = z4, pb2 = z4;
        if (ok0) { pa.x  = phi_(ka.x); pa.y  = phi_(ka.y); pa.z  = phi_(ka.z); pa.w  = phi_(ka.w); }
        if (ok1) { pb2.x = phi_(kb.x); pb2.y = phi_(kb.y); pb2.z = phi_(kb.z); pb2.w = phi_(kb.w); }
        __syncthreads();                // previous round's LDS reads done
        *(float4*)&phk[sr][sc]      = pa;
        *(float4*)&phk[sr + 16][sc] = pb2;
        *(float4*)&vvv[sr][sc]      = va;   // already 0 when !ok
        *(float4*)&vvv[sr + 16][sc] = vb;
        __syncthreads();

        // prefetch next round
        ok0 = (l0 + 32 + sr) < lend;
        ok1 = (l0 + 32 + sr + 16) < lend;
        ka = z4; kb = z4; va = z4; vb = z4;
        if (ok0) {
            const size_t b = (size_t)(l0 + 32 + sr) * ROWSTRIDE + bh_off + sc;
            ka = *(const float4*)(K + b);  va = *(const float4*)(V + b);
        }
        if (ok1) {
            const size_t b = (size_t)(l0 + 32 + sr + 16) * ROWSTRIDE + bh_off + sc;
            kb = *(const float4*)(K + b);  vb = *(const float4*)(V + b);
        }

        // compute: this wave's 8 rows of the staged 32
        #pragma unroll
        for (int r = 0; r < 8; ++r) {
            const int rr = w * 8 + r;
            float4 a0 = *(const float4*)&phk[rr][d0];
            float4 a1 = *(const float4*)&phk[rr][d0 + 4];
            float4 b0 = *(const float4*)&vvv[rr][e0];
            float4 b1 = *(const float4*)&vvv[rr][e0 + 4];
            float av[8] = {a0.x,a0.y,a0.z,a0.w,a1.x,a1.y,a1.z,a1.w};
            float bv[8] = {b0.x,b0.y,b0.z,b0.w,b1.x,b1.y,b1.z,b1.w};
            #pragma unroll
            for (int i = 0; i < 8; ++i) {
                ks[i] += av[i];
                #pragma unroll
                for (int j = 0; j < 8; ++j)
                    acc[i][j] = fmaf(av[i], bv[j], acc[i][j]);
            }
        }
    }

    // ---- block reduce: waves 1..3 dump to LDS, wave 0 adds and stores ----
    __syncthreads();
    if (w > 0) {
        float* sl = sm + (w - 1) * 4160;
        #pragma unroll
        for (int i = 0; i < 8; ++i) {
            *(float4*)&sl[(d0 + i) * 64 + e0]     = make_float4(acc[i][0], acc[i][1], acc[i][2], acc[i][3]);
            *(float4*)&sl[(d0 + i) * 64 + e0 + 4] = make_float4(acc[i][4], acc[i][5], acc[i][6], acc[i][7]);
        }
        if (e0 == 0) {
            #pragma unroll
            for (int i = 0; i < 8; ++i) sl[4096 + d0 + i] = ks[i];
        }
    }
    __syncthreads();
    if (w == 0) {
        float* pb = part + ((size_t)c * NBH + bh) * KVSZ;
        #pragma unroll
        for (int i = 0; i < 8; ++i) {
            #pragma unroll
            for (int jq = 0; jq < 2; ++jq) {
                const int off = (d0 + i) * 64 + e0 + jq * 4;
                float4 s0 = *(const float4*)&sm[off];
                float4 s1 = *(const float4*)&sm[4160 + off];
                float4 s2 = *(const float4*)&sm[8320 + off];
                float4 o;
                o.x = acc[i][jq*4+0] + s0.x + s1.x + s2.x;
                o.y = acc[i][jq*4+1] + s0.y + s1.y + s2.y;
                o.z = acc[i][jq*4+2] + s0.z + s1.z + s2.z;
                o.w = acc[i][jq*4+3] + s0.w + s1.w + s2.w;
                *(float4*)&pb[off] = o;
            }
        }
        if (e0 == 0) {
            #pragma unroll
            for (int i = 0; i < 8; ++i) {
                const int dd = 4096 + d0 + i;
                pb[dd] = ks[i] + sm[dd] + sm[4160 + dd] + sm[8320 + dd];
            }
        }
    }
}

// ---------------- Pass 1b: reduce partials (float4) ----------------
__global__ __launch_bounds__(256) void kv_reduce_kernel(
    const float* __restrict__ part, float* __restrict__ fin, int nchunk)
{
    const int i4 = blockIdx.x * 256 + threadIdx.x;
    if (i4 >= (NBH * KVSZ) / 4) return;
    const float4* p4 = (const float4*)part;
    float4 s = make_float4(0.f, 0.f, 0.f, 0.f);
    for (int cc = 0; cc < nchunk; ++cc) {
        float4 v = p4[(size_t)cc * (NBH * KVSZ / 4) + i4];
        s.x += v.x; s.y += v.y; s.z += v.z; s.w += v.w;
    }
    ((float4*)fin)[i4] = s;
}

// ---------------- Pass 2: per-token output ----------------
// grid = 2048 (64 token-tiles x 32 bh), block = 64 (1 wave). lane = token.
// phiQ tile transposed into padded LDS [64][65] (conflict-free row reads).
// kv[d][e] is wave-uniform -> scalar (s_load) operand of v_fma: the inner
// loop is pure VALU, 1 ds_read_b32 per d serving 65 FMAs.
__global__ __launch_bounds__(64) void attn_out_kernel(
    const float* __restrict__ Q, const float* __restrict__ fin,
    float* __restrict__ out)
{
    __shared__ float pq[64 * 65];      // 16.64 KB, +1 pad

    const int lane = threadIdx.x;      // 0..63
    const int bh   = blockIdx.x & 31;
    const int tile = blockIdx.x >> 5;  // 0..63
    const int lt0  = tile * 64;

    const float* __restrict__ fb = fin + (size_t)bh * KVSZ;

    // stage phi(Q) tile: token t = r*4 + (lane>>4), cols (lane&15)*4
    const int st = lane >> 4;
    const int sc = (lane & 15) * 4;
    #pragma unroll
    for (int r = 0; r < 16; ++r) {
        const int t = r * 4 + st;
        float4 q4 = *(const float4*)(Q + (size_t)(lt0 + t) * ROWSTRIDE + (size_t)bh * 64 + sc);
        float4 p4;
        p4.x = phi_(q4.x); p4.y = phi_(q4.y); p4.z = phi_(q4.z); p4.w = phi_(q4.w);
        *(float4*)&pq[t * 65 + sc] = p4;
    }
    __syncthreads();

    float acc[64];
    #pragma unroll
    for (int e = 0; e < 64; ++e) acc[e] = 0.f;
    float den = 0.f;

    const float* __restrict__ prow = &pq[lane * 65];
    #pragma unroll 4
    for (int d = 0; d < 64; ++d) {
        const float p = prow[d];                    // ds_read_b32, conflict-free
        den = fmaf(p, fb[4096 + d], den);           // uniform -> SGPR operand
        const float* __restrict__ kr = fb + d * 64; // uniform row
        #pragma unroll
        for (int e4 = 0; e4 < 16; ++e4) {
            const float4 kq = *(const float4*)(kr + e4 * 4);
            acc[e4*4+0] = fmaf(p, kq.x, acc[e4*4+0]);
            acc[e4*4+1] = fmaf(p, kq.y, acc[e4*4+1]);
            acc[e4*4+2] = fmaf(p, kq.z, acc[e4*4+2]);
            acc[e4*4+3] = fmaf(p, kq.w, acc[e4*4+3]);
        }
    }

    const float inv = 1.0f / (den + EPS_);

    // transpose through (now dead) pq for coalesced stores
    #pragma unroll
    for (int e4 = 0; e4 < 16; ++e4) {
        float4 o4 = make_float4(acc[e4*4+0] * inv, acc[e4*4+1] * inv,
                                acc[e4*4+2] * inv, acc[e4*4+3] * inv);
        *(float4*)&pq[lane * 65 + e4 * 4] = o4;
    }
    __syncthreads();
    #pragma unroll
    for (int r = 0; r < 16; ++r) {
        const int t = r * 4 + st;
        float4 o4 = *(const float4*)&pq[t * 65 + sc];
        *(float4*)(out + (size_t)(lt0 + t) * ROWSTRIDE + (size_t)bh * 64 + sc) = o4;
    }
}

extern "C" void kernel_launch(void* const* d_in, const int* in_sizes, int n_in,
                              void* d_out, int out_size, void* d_ws, size_t ws_size,
                              hipStream_t stream) {
    const float* Q = (const float*)d_in[0];
    const float* K = (const float*)d_in[1];
    const float* V = (const float*)d_in[2];
    float* outp = (float*)d_out;
    float* ws   = (float*)d_ws;

    const size_t slab = (size_t)NBH * KVSZ;          // 133120 floats = 532 KB
    const size_t cap  = ws_size / (slab * sizeof(float));

    int nchunk;
    float* fin = ws;
    float* part;
    bool do_reduce;
    if (cap >= 3) {                 // final slab + >=2 partial slabs
        size_t n = cap - 1;
        if (n > 32) n = 32;
        nchunk = (int)n;
        part = ws + slab;
        do_reduce = true;
    } else {                        // tiny ws: single chunk, write final directly
        nchunk = 1;
        part = ws;
        do_reduce = false;
    }
    const int Lc = (L_TOT + nchunk - 1) / nchunk;

    hipLaunchKernelGGL(kv_partial_kernel, dim3(nchunk, NBH), dim3(256), 0, stream,
                       K, V, part, Lc);
    if (do_reduce) {
        const int nb = ((NBH * KVSZ) / 4 + 255) / 256;
        hipLaunchKernelGGL(kv_reduce_kernel, dim3(nb), dim3(256), 0, stream,
                           part, fin, nchunk);
    }
    hipLaunchKernelGGL(attn_out_kernel, dim3(2048), dim3(64), 0, stream,
                       Q, fin, outp);
}

// Round 4
// 65.908 us; speedup vs baseline: 1.1411x; 1.0325x over previous
//
#include <hip/hip_runtime.h>
#include <math.h>

// LinearAttention: L=4096, B=4, H=8, D=Dv=64, fp32.
// out[l,b,h,e] = (phiQ[l,bh,:] . kv[bh,:,e]) / (phiQ[l,bh,:] . ksum[bh,:] + eps)
// kv[bh,d,e] = sum_l phiK[l,bh,d] * V[l,bh,e]   (GLOBAL sum, not causal)
// phi(x) = elu(x)+1 = x>0 ? x+1 : exp(x)

#define L_TOT 4096
#define NBH   32            // B*H
#define ROWSTRIDE 2048      // B*H*D floats between consecutive l
#define KVSZ  4160          // 64*64 kv + 64 ksum
#define EPS_  1e-6f

__device__ __forceinline__ float phi_(float x) {
    return x > 0.0f ? x + 1.0f : __expf(x);
}

// ---------------- Pass 1: partial kv + ksum per (chunk, bh) ----------------
// grid = (nchunk, 32), block = 256 (4 waves). Each WAVE owns a full 64x64 kv
// accumulator (8x8 tile per lane = 64 VGPRs); 4 ds_read_b128 per row per wave
// (16 FMAs per b128). Waves block-reduce through LDS at the end.
__global__ __launch_bounds__(256) void kv_partial_kernel(
    const float* __restrict__ K, const float* __restrict__ V,
    float* __restrict__ part, int Lc)
{
    __shared__ float sm[12480];                    // 48.75 KB
    float (*phk)[64] = (float(*)[64])sm;           // [32][64] staged phiK
    float (*vvv)[64] = (float(*)[64])(sm + 2048);  // [32][64] staged V

    const int tid  = threadIdx.x;
    const int w    = tid >> 6;          // wave 0..3
    const int lane = tid & 63;
    const int c    = blockIdx.x;
    const int bh   = blockIdx.y;
    const int l0c  = c * Lc;
    const int lend = min(l0c + Lc, L_TOT);

    const int d0 = (lane >> 3) * 8;     // lane's 8 kv-rows (d)
    const int e0 = (lane & 7) * 8;      // lane's 8 kv-cols (e)

    const int sr = tid >> 4;            // staging row 0..15 (and +16)
    const int sc = (tid & 15) * 4;      // staging col (float4)

    float acc[8][8];
    #pragma unroll
    for (int i = 0; i < 8; ++i)
        #pragma unroll
        for (int j = 0; j < 8; ++j) acc[i][j] = 0.f;
    float ks[8] = {0.f,0.f,0.f,0.f,0.f,0.f,0.f,0.f};

    const size_t bh_off = (size_t)bh * 64;

    // prologue prefetch (rows l0c+sr, l0c+sr+16)
    float4 z4 = make_float4(0.f, 0.f, 0.f, 0.f);
    bool ok0 = (l0c + sr) < lend;
    bool ok1 = (l0c + sr + 16) < lend;
    float4 ka = z4, kb = z4, va = z4, vb = z4;
    if (ok0) {
        const size_t b = (size_t)(l0c + sr) * ROWSTRIDE + bh_off + sc;
        ka = *(const float4*)(K + b);  va = *(const float4*)(V + b);
    }
    if (ok1) {
        const size_t b = (size_t)(l0c + sr + 16) * ROWSTRIDE + bh_off + sc;
        kb = *(const float4*)(K + b);  vb = *(const float4*)(V + b);
    }

    for (int l0 = l0c; l0 < lend; l0 += 32) {
        float4 pa = z4, pb2 = z4;
        if (ok0) { pa.x  = phi_(ka.x); pa.y  = phi_(ka.y); pa.z  = phi_(ka.z); pa.w  = phi_(ka.w); }
        if (ok1) { pb2.x = phi_(kb.x); pb2.y = phi_(kb.y); pb2.z = phi_(kb.z); pb2.w = phi_(kb.w); }
        __syncthreads();                // previous round's LDS reads done
        *(float4*)&phk[sr][sc]      = pa;
        *(float4*)&phk[sr + 16][sc] = pb2;
        *(float4*)&vvv[sr][sc]      = va;   // already 0 when !ok
        *(float4*)&vvv[sr + 16][sc] = vb;
        __syncthreads();

        // prefetch next round
        ok0 = (l0 + 32 + sr) < lend;
        ok1 = (l0 + 32 + sr + 16) < lend;
        ka = z4; kb = z4; va = z4; vb = z4;
        if (ok0) {
            const size_t b = (size_t)(l0 + 32 + sr) * ROWSTRIDE + bh_off + sc;
            ka = *(const float4*)(K + b);  va = *(const float4*)(V + b);
        }
        if (ok1) {
            const size_t b = (size_t)(l0 + 32 + sr + 16) * ROWSTRIDE + bh_off + sc;
            kb = *(const float4*)(K + b);  vb = *(const float4*)(V + b);
        }

        // compute: this wave's 8 rows of the staged 32
        #pragma unroll
        for (int r = 0; r < 8; ++r) {
            const int rr = w * 8 + r;
            float4 a0 = *(const float4*)&phk[rr][d0];
            float4 a1 = *(const float4*)&phk[rr][d0 + 4];
            float4 b0 = *(const float4*)&vvv[rr][e0];
            float4 b1 = *(const float4*)&vvv[rr][e0 + 4];
            float av[8] = {a0.x,a0.y,a0.z,a0.w,a1.x,a1.y,a1.z,a1.w};
            float bv[8] = {b0.x,b0.y,b0.z,b0.w,b1.x,b1.y,b1.z,b1.w};
            #pragma unroll
            for (int i = 0; i < 8; ++i) {
                ks[i] += av[i];
                #pragma unroll
                for (int j = 0; j < 8; ++j)
                    acc[i][j] = fmaf(av[i], bv[j], acc[i][j]);
            }
        }
    }

    // ---- block reduce: waves 1..3 dump to LDS, wave 0 adds and stores ----
    __syncthreads();
    if (w > 0) {
        float* sl = sm + (w - 1) * 4160;
        #pragma unroll
        for (int i = 0; i < 8; ++i) {
            *(float4*)&sl[(d0 + i) * 64 + e0]     = make_float4(acc[i][0], acc[i][1], acc[i][2], acc[i][3]);
            *(float4*)&sl[(d0 + i) * 64 + e0 + 4] = make_float4(acc[i][4], acc[i][5], acc[i][6], acc[i][7]);
        }
        if (e0 == 0) {
            #pragma unroll
            for (int i = 0; i < 8; ++i) sl[4096 + d0 + i] = ks[i];
        }
    }
    __syncthreads();
    if (w == 0) {
        float* pb = part + ((size_t)c * NBH + bh) * KVSZ;
        #pragma unroll
        for (int i = 0; i < 8; ++i) {
            #pragma unroll
            for (int jq = 0; jq < 2; ++jq) {
                const int off = (d0 + i) * 64 + e0 + jq * 4;
                float4 s0 = *(const float4*)&sm[off];
                float4 s1 = *(const float4*)&sm[4160 + off];
                float4 s2 = *(const float4*)&sm[8320 + off];
                float4 o;
                o.x = acc[i][jq*4+0] + s0.x + s1.x + s2.x;
                o.y = acc[i][jq*4+1] + s0.y + s1.y + s2.y;
                o.z = acc[i][jq*4+2] + s0.z + s1.z + s2.z;
                o.w = acc[i][jq*4+3] + s0.w + s1.w + s2.w;
                *(float4*)&pb[off] = o;
            }
        }
        if (e0 == 0) {
            #pragma unroll
            for (int i = 0; i < 8; ++i) {
                const int dd = 4096 + d0 + i;
                pb[dd] = ks[i] + sm[dd] + sm[4160 + dd] + sm[8320 + dd];
            }
        }
    }
}

// ---------------- Pass 1b: reduce partials (float4) ----------------
__global__ __launch_bounds__(256) void kv_reduce_kernel(
    const float* __restrict__ part, float* __restrict__ fin, int nchunk)
{
    const int i4 = blockIdx.x * 256 + threadIdx.x;
    if (i4 >= (NBH * KVSZ) / 4) return;
    const float4* p4 = (const float4*)part;
    float4 s = make_float4(0.f, 0.f, 0.f, 0.f);
    for (int cc = 0; cc < nchunk; ++cc) {
        float4 v = p4[(size_t)cc * (NBH * KVSZ / 4) + i4];
        s.x += v.x; s.y += v.y; s.z += v.z; s.w += v.w;
    }
    ((float4*)fin)[i4] = s;
}

// ---------------- Pass 2: register-tiled GEMM per wave ----------------
// grid = 512 (16 token-blocks x 32 bh), block = 256 (4 waves). Each wave
// computes a 64tok x 64e tile; lane owns 8x8 (64 VGPR acc). A (phiQ^T) from
// per-wave XOR-swizzled LDS (2 ds_read_b128/d); B (kv row) via global float4
// (16 KB table, L1-resident, cache-line dedup); ksum via uniform s_load.
// Denominator computed redundantly per lane from its A-frag (no reduce).
__global__ __launch_bounds__(256) void attn_out_kernel(
    const float* __restrict__ Q, const float* __restrict__ fin,
    float* __restrict__ out)
{
    __shared__ __align__(16) float pqT[4][4096];   // 64 KB: per-wave [d][swz(t)]

    const int tid  = threadIdx.x;
    const int lane = tid & 63;
    const int w    = tid >> 6;
    const int bh   = blockIdx.x & 31;
    const int tile0 = (blockIdx.x >> 5) * 256 + w * 64;   // wave's 64 tokens

    const float* __restrict__ fb = fin + (size_t)bh * KVSZ;
    float* __restrict__ pw = pqT[w];

    // ---- stage phi(Q)^T with float4-block XOR swizzle ----
    // token t = 4r + s (s = lane>>4), d-cols c..c+3 (c = (lane&15)*4).
    // write pw[d*64 + (j ^ (d&15))*4 + s] where j = t>>2 = r.
    {
        const int s = lane >> 4;
        const int c = (lane & 15) * 4;
        #pragma unroll
        for (int r = 0; r < 16; ++r) {
            const int t = r * 4 + s;
            float4 q4 = *(const float4*)(Q + (size_t)(tile0 + t) * ROWSTRIDE
                                           + (size_t)bh * 64 + c);
            float p0 = phi_(q4.x), p1 = phi_(q4.y), p2 = phi_(q4.z), p3 = phi_(q4.w);
            pw[(c + 0) * 64 + ((r ^ ((c + 0) & 15)) << 2) + s] = p0;
            pw[(c + 1) * 64 + ((r ^ ((c + 1) & 15)) << 2) + s] = p1;
            pw[(c + 2) * 64 + ((r ^ ((c + 2) & 15)) << 2) + s] = p2;
            pw[(c + 3) * 64 + ((r ^ ((c + 3) & 15)) << 2) + s] = p3;
        }
    }
    __syncthreads();

    // ---- 64x64x64 GEMM, lane tile 8 tok x 8 e ----
    const int t0 = (lane >> 3) * 8;      // lane's 8 tokens (rows)
    const int e0 = (lane & 7) * 8;       // lane's 8 e (cols)
    const int jb = t0 >> 2;              // even f4-block index of t0

    float acc[8][8];
    #pragma unroll
    for (int i = 0; i < 8; ++i)
        #pragma unroll
        for (int j = 0; j < 8; ++j) acc[i][j] = 0.f;
    float den[8] = {0.f,0.f,0.f,0.f,0.f,0.f,0.f,0.f};

    #pragma unroll 4
    for (int d = 0; d < 64; ++d) {
        const int x = d & 15;
        float4 a0 = *(const float4*)&pw[d * 64 + ((jb       ^ x) << 2)];
        float4 a1 = *(const float4*)&pw[d * 64 + (((jb + 1) ^ x) << 2)];
        float4 b0 = *(const float4*)(fb + d * 64 + e0);        // L1-resident
        float4 b1 = *(const float4*)(fb + d * 64 + e0 + 4);
        const float ksv = fb[4096 + d];                         // uniform s_load
        float av[8] = {a0.x,a0.y,a0.z,a0.w,a1.x,a1.y,a1.z,a1.w};
        float bv[8] = {b0.x,b0.y,b0.z,b0.w,b1.x,b1.y,b1.z,b1.w};
        #pragma unroll
        for (int i = 0; i < 8; ++i) {
            den[i] = fmaf(av[i], ksv, den[i]);
            #pragma unroll
            for (int j = 0; j < 8; ++j)
                acc[i][j] = fmaf(av[i], bv[j], acc[i][j]);
        }
    }

    // ---- epilogue: divide and store (8 rows x 2 float4) ----
    #pragma unroll
    for (int i = 0; i < 8; ++i) {
        const float inv = 1.0f / (den[i] + EPS_);
        float* op = out + (size_t)(tile0 + t0 + i) * ROWSTRIDE + (size_t)bh * 64 + e0;
        *(float4*)op       = make_float4(acc[i][0]*inv, acc[i][1]*inv,
                                         acc[i][2]*inv, acc[i][3]*inv);
        *(float4*)(op + 4) = make_float4(acc[i][4]*inv, acc[i][5]*inv,
                                         acc[i][6]*inv, acc[i][7]*inv);
    }
}

extern "C" void kernel_launch(void* const* d_in, const int* in_sizes, int n_in,
                              void* d_out, int out_size, void* d_ws, size_t ws_size,
                              hipStream_t stream) {
    const float* Q = (const float*)d_in[0];
    const float* K = (const float*)d_in[1];
    const float* V = (const float*)d_in[2];
    float* outp = (float*)d_out;
    float* ws   = (float*)d_ws;

    const size_t slab = (size_t)NBH * KVSZ;          // 133120 floats = 532 KB
    const size_t cap  = ws_size / (slab * sizeof(float));

    int nchunk;
    float* fin = ws;
    float* part;
    bool do_reduce;
    if (cap >= 3) {                 // final slab + >=2 partial slabs
        size_t n = cap - 1;
        if (n > 32) n = 32;
        nchunk = (int)n;
        part = ws + slab;
        do_reduce = true;
    } else {                        // tiny ws: single chunk, write final directly
        nchunk = 1;
        part = ws;
        do_reduce = false;
    }
    const int Lc = (L_TOT + nchunk - 1) / nchunk;

    hipLaunchKernelGGL(kv_partial_kernel, dim3(nchunk, NBH), dim3(256), 0, stream,
                       K, V, part, Lc);
    if (do_reduce) {
        const int nb = ((NBH * KVSZ) / 4 + 255) / 256;
        hipLaunchKernelGGL(kv_reduce_kernel, dim3(nb), dim3(256), 0, stream,
                           part, fin, nchunk);
    }
    hipLaunchKernelGGL(attn_out_kernel, dim3(512), dim3(256), 0, stream,
                       Q, fin, outp);
}

// Round 5
// 59.281 us; speedup vs baseline: 1.2687x; 1.1118x over previous
//
#include <hip/hip_runtime.h>
#include <math.h>

// LinearAttention: L=4096, B=4, H=8, D=Dv=64, fp32.
// out[l,b,h,e] = (phiQ[l,bh,:] . kv[bh,:,e]) / (phiQ[l,bh,:] . ksum[bh,:] + eps)
// kv[bh,d,e] = sum_l phiK[l,bh,d] * V[l,bh,e]   (GLOBAL sum, not causal)
// phi(x) = elu(x)+1 = x>0 ? x+1 : exp(x)

#define L_TOT 4096
#define NBH   32            // B*H
#define ROWSTRIDE 2048      // B*H*D floats between consecutive l
#define KVSZ  4160          // 64*64 kv + 64 ksum
#define EPS_  1e-6f

__device__ __forceinline__ float phi_(float x) {
    return x > 0.0f ? x + 1.0f : __expf(x);
}

// ---------------- Pass 1: partial kv + ksum per (chunk, bh) ----------------
// grid = (16, 32) = 512 blocks -> exactly 2 blocks/CU, no tail. 4 waves;
// each WAVE owns a full 64x64 kv accumulator (8x8 tile per lane); 4
// ds_read_b128 per row per wave (16 FMAs per b128). LDS block-reduce at end.
__global__ __launch_bounds__(256) void kv_partial_kernel(
    const float* __restrict__ K, const float* __restrict__ V,
    float* __restrict__ part, int Lc)
{
    __shared__ float sm[12480];                    // 48.75 KB
    float (*phk)[64] = (float(*)[64])sm;           // [32][64] staged phiK
    float (*vvv)[64] = (float(*)[64])(sm + 2048);  // [32][64] staged V

    const int tid  = threadIdx.x;
    const int w    = tid >> 6;          // wave 0..3
    const int lane = tid & 63;
    const int c    = blockIdx.x;
    const int bh   = blockIdx.y;
    const int l0c  = c * Lc;
    const int lend = min(l0c + Lc, L_TOT);

    const int d0 = (lane >> 3) * 8;     // lane's 8 kv-rows (d)
    const int e0 = (lane & 7) * 8;      // lane's 8 kv-cols (e)

    const int sr = tid >> 4;            // staging row 0..15 (and +16)
    const int sc = (tid & 15) * 4;      // staging col (float4)

    float acc[8][8];
    #pragma unroll
    for (int i = 0; i < 8; ++i)
        #pragma unroll
        for (int j = 0; j < 8; ++j) acc[i][j] = 0.f;
    float ks[8] = {0.f,0.f,0.f,0.f,0.f,0.f,0.f,0.f};

    const size_t bh_off = (size_t)bh * 64;

    // prologue prefetch (rows l0c+sr, l0c+sr+16)
    float4 z4 = make_float4(0.f, 0.f, 0.f, 0.f);
    bool ok0 = (l0c + sr) < lend;
    bool ok1 = (l0c + sr + 16) < lend;
    float4 ka = z4, kb = z4, va = z4, vb = z4;
    if (ok0) {
        const size_t b = (size_t)(l0c + sr) * ROWSTRIDE + bh_off + sc;
        ka = *(const float4*)(K + b);  va = *(const float4*)(V + b);
    }
    if (ok1) {
        const size_t b = (size_t)(l0c + sr + 16) * ROWSTRIDE + bh_off + sc;
        kb = *(const float4*)(K + b);  vb = *(const float4*)(V + b);
    }

    for (int l0 = l0c; l0 < lend; l0 += 32) {
        float4 pa = z4, pb2 = z4;
        if (ok0) { pa.x  = phi_(ka.x); pa.y  = phi_(ka.y); pa.z  = phi_(ka.z); pa.w  = phi_(ka.w); }
        if (ok1) { pb2.x = phi_(kb.x); pb2.y = phi_(kb.y); pb2.z = phi_(kb.z); pb2.w = phi_(kb.w); }
        __syncthreads();                // previous round's LDS reads done
        *(float4*)&phk[sr][sc]      = pa;
        *(float4*)&phk[sr + 16][sc] = pb2;
        *(float4*)&vvv[sr][sc]      = va;   // already 0 when !ok
        *(float4*)&vvv[sr + 16][sc] = vb;
        __syncthreads();

        // prefetch next round
        ok0 = (l0 + 32 + sr) < lend;
        ok1 = (l0 + 32 + sr + 16) < lend;
        ka = z4; kb = z4; va = z4; vb = z4;
        if (ok0) {
            const size_t b = (size_t)(l0 + 32 + sr) * ROWSTRIDE + bh_off + sc;
            ka = *(const float4*)(K + b);  va = *(const float4*)(V + b);
        }
        if (ok1) {
            const size_t b = (size_t)(l0 + 32 + sr + 16) * ROWSTRIDE + bh_off + sc;
            kb = *(const float4*)(K + b);  vb = *(const float4*)(V + b);
        }

        // compute: this wave's 8 rows of the staged 32
        #pragma unroll
        for (int r = 0; r < 8; ++r) {
            const int rr = w * 8 + r;
            float4 a0 = *(const float4*)&phk[rr][d0];
            float4 a1 = *(const float4*)&phk[rr][d0 + 4];
            float4 b0 = *(const float4*)&vvv[rr][e0];
            float4 b1 = *(const float4*)&vvv[rr][e0 + 4];
            float av[8] = {a0.x,a0.y,a0.z,a0.w,a1.x,a1.y,a1.z,a1.w};
            float bv[8] = {b0.x,b0.y,b0.z,b0.w,b1.x,b1.y,b1.z,b1.w};
            #pragma unroll
            for (int i = 0; i < 8; ++i) {
                ks[i] += av[i];
                #pragma unroll
                for (int j = 0; j < 8; ++j)
                    acc[i][j] = fmaf(av[i], bv[j], acc[i][j]);
            }
        }
    }

    // ---- block reduce: waves 1..3 dump to LDS, wave 0 adds and stores ----
    __syncthreads();
    if (w > 0) {
        float* sl = sm + (w - 1) * 4160;
        #pragma unroll
        for (int i = 0; i < 8; ++i) {
            *(float4*)&sl[(d0 + i) * 64 + e0]     = make_float4(acc[i][0], acc[i][1], acc[i][2], acc[i][3]);
            *(float4*)&sl[(d0 + i) * 64 + e0 + 4] = make_float4(acc[i][4], acc[i][5], acc[i][6], acc[i][7]);
        }
        if (e0 == 0) {
            #pragma unroll
            for (int i = 0; i < 8; ++i) sl[4096 + d0 + i] = ks[i];
        }
    }
    __syncthreads();
    if (w == 0) {
        float* pb = part + ((size_t)c * NBH + bh) * KVSZ;
        #pragma unroll
        for (int i = 0; i < 8; ++i) {
            #pragma unroll
            for (int jq = 0; jq < 2; ++jq) {
                const int off = (d0 + i) * 64 + e0 + jq * 4;
                float4 s0 = *(const float4*)&sm[off];
                float4 s1 = *(const float4*)&sm[4160 + off];
                float4 s2 = *(const float4*)&sm[8320 + off];
                float4 o;
                o.x = acc[i][jq*4+0] + s0.x + s1.x + s2.x;
                o.y = acc[i][jq*4+1] + s0.y + s1.y + s2.y;
                o.z = acc[i][jq*4+2] + s0.z + s1.z + s2.z;
                o.w = acc[i][jq*4+3] + s0.w + s1.w + s2.w;
                *(float4*)&pb[off] = o;
            }
        }
        if (e0 == 0) {
            #pragma unroll
            for (int i = 0; i < 8; ++i) {
                const int dd = 4096 + d0 + i;
                pb[dd] = ks[i] + sm[dd] + sm[4160 + dd] + sm[8320 + dd];
            }
        }
    }
}

// ---------------- Pass 1b: reduce partials (float4) ----------------
__global__ __launch_bounds__(256) void kv_reduce_kernel(
    const float* __restrict__ part, float* __restrict__ fin, int nchunk)
{
    const int i4 = blockIdx.x * 256 + threadIdx.x;
    if (i4 >= (NBH * KVSZ) / 4) return;
    const float4* p4 = (const float4*)part;
    float4 s = make_float4(0.f, 0.f, 0.f, 0.f);
    for (int cc = 0; cc < nchunk; ++cc) {
        float4 v = p4[(size_t)cc * (NBH * KVSZ / 4) + i4];
        s.x += v.x; s.y += v.y; s.z += v.z; s.w += v.w;
    }
    ((float4*)fin)[i4] = s;
}

// ---------------- Pass 2: register-tiled GEMM per wave, kv in LDS ----------
// grid = 512 (16 token-blocks x 32 bh), block = 256 (4 waves). Each wave
// computes a 64tok x 64e tile; lane owns 8x8 (64 VGPR acc). A (phiQ^T) from
// per-wave XOR-swizzled LDS; B (kv row) from a block-local LDS copy of the
// 16 KB kv table (no global/L1 traffic in the loop); ksum via batched uniform
// s_load (256 B, scalar K$). LDS = 64 + 16 = 80 KB -> exactly 2 blocks/CU.
__global__ __launch_bounds__(256) void attn_out_kernel(
    const float* __restrict__ Q, const float* __restrict__ fin,
    float* __restrict__ out)
{
    __shared__ __align__(16) float pqT[4][4096];   // 64 KB: per-wave [d][swz(t)]
    __shared__ __align__(16) float skv[4096];      // 16 KB: kv[d][e]

    const int tid  = threadIdx.x;
    const int lane = tid & 63;
    const int w    = tid >> 6;
    const int bh   = blockIdx.x & 31;
    const int tile0 = (blockIdx.x >> 5) * 256 + w * 64;   // wave's 64 tokens

    const float* __restrict__ fb = fin + (size_t)bh * KVSZ;
    float* __restrict__ pw = pqT[w];

    // ---- copy kv table into LDS (1024 float4, coalesced) ----
    {
        const float4* __restrict__ fb4 = (const float4*)fb;
        float4* __restrict__ sk4 = (float4*)skv;
        #pragma unroll
        for (int k = 0; k < 4; ++k)
            sk4[tid + k * 256] = fb4[tid + k * 256];
    }

    // ---- stage phi(Q)^T with float4-block XOR swizzle ----
    // token t = 4r + s (s = lane>>4), d-cols c..c+3 (c = (lane&15)*4).
    // write pw[d*64 + (j ^ (d&15))*4 + s] where j = t>>2 = r.
    {
        const int s = lane >> 4;
        const int c = (lane & 15) * 4;
        #pragma unroll
        for (int r = 0; r < 16; ++r) {
            const int t = r * 4 + s;
            float4 q4 = *(const float4*)(Q + (size_t)(tile0 + t) * ROWSTRIDE
                                           + (size_t)bh * 64 + c);
            float p0 = phi_(q4.x), p1 = phi_(q4.y), p2 = phi_(q4.z), p3 = phi_(q4.w);
            pw[(c + 0) * 64 + ((r ^ ((c + 0) & 15)) << 2) + s] = p0;
            pw[(c + 1) * 64 + ((r ^ ((c + 1) & 15)) << 2) + s] = p1;
            pw[(c + 2) * 64 + ((r ^ ((c + 2) & 15)) << 2) + s] = p2;
            pw[(c + 3) * 64 + ((r ^ ((c + 3) & 15)) << 2) + s] = p3;
        }
    }
    __syncthreads();

    // ---- 64x64x64 GEMM, lane tile 8 tok x 8 e ----
    const int t0 = (lane >> 3) * 8;      // lane's 8 tokens (rows)
    const int e0 = (lane & 7) * 8;       // lane's 8 e (cols)
    const int jb = t0 >> 2;              // even f4-block index of t0

    float acc[8][8];
    #pragma unroll
    for (int i = 0; i < 8; ++i)
        #pragma unroll
        for (int j = 0; j < 8; ++j) acc[i][j] = 0.f;
    float den[8] = {0.f,0.f,0.f,0.f,0.f,0.f,0.f,0.f};

    #pragma unroll 4
    for (int d = 0; d < 64; ++d) {
        const int x = d & 15;
        float4 a0 = *(const float4*)&pw[d * 64 + ((jb       ^ x) << 2)];
        float4 a1 = *(const float4*)&pw[d * 64 + (((jb + 1) ^ x) << 2)];
        float4 b0 = *(const float4*)&skv[d * 64 + e0];
        float4 b1 = *(const float4*)&skv[d * 64 + e0 + 4];
        const float ksv = fb[4096 + d];          // uniform s_load, K$-resident
        float av[8] = {a0.x,a0.y,a0.z,a0.w,a1.x,a1.y,a1.z,a1.w};
        float bv[8] = {b0.x,b0.y,b0.z,b0.w,b1.x,b1.y,b1.z,b1.w};
        #pragma unroll
        for (int i = 0; i < 8; ++i) {
            den[i] = fmaf(av[i], ksv, den[i]);
            #pragma unroll
            for (int j = 0; j < 8; ++j)
                acc[i][j] = fmaf(av[i], bv[j], acc[i][j]);
        }
    }

    // ---- epilogue: divide and store (8 rows x 2 float4) ----
    #pragma unroll
    for (int i = 0; i < 8; ++i) {
        const float inv = 1.0f / (den[i] + EPS_);
        float* op = out + (size_t)(tile0 + t0 + i) * ROWSTRIDE + (size_t)bh * 64 + e0;
        *(float4*)op       = make_float4(acc[i][0]*inv, acc[i][1]*inv,
                                         acc[i][2]*inv, acc[i][3]*inv);
        *(float4*)(op + 4) = make_float4(acc[i][4]*inv, acc[i][5]*inv,
                                         acc[i][6]*inv, acc[i][7]*inv);
    }
}

extern "C" void kernel_launch(void* const* d_in, const int* in_sizes, int n_in,
                              void* d_out, int out_size, void* d_ws, size_t ws_size,
                              hipStream_t stream) {
    const float* Q = (const float*)d_in[0];
    const float* K = (const float*)d_in[1];
    const float* V = (const float*)d_in[2];
    float* outp = (float*)d_out;
    float* ws   = (float*)d_ws;

    const size_t slab = (size_t)NBH * KVSZ;          // 133120 floats = 532 KB
    const size_t cap  = ws_size / (slab * sizeof(float));

    int nchunk;
    float* fin = ws;
    float* part;
    bool do_reduce;
    if (cap >= 3) {                 // final slab + >=2 partial slabs
        size_t n = cap - 1;
        if (n > 16) n = 16;         // 16 chunks -> 512 blocks = 2/CU, no tail
        nchunk = (int)n;
        part = ws + slab;
        do_reduce = true;
    } else {                        // tiny ws: single chunk, write final directly
        nchunk = 1;
        part = ws;
        do_reduce = false;
    }
    const int Lc = (L_TOT + nchunk - 1) / nchunk;

    hipLaunchKernelGGL(kv_partial_kernel, dim3(nchunk, NBH), dim3(256), 0, stream,
                       K, V, part, Lc);
    if (do_reduce) {
        const int nb = ((NBH * KVSZ) / 4 + 255) / 256;
        hipLaunchKernelGGL(kv_reduce_kernel, dim3(nb), dim3(256), 0, stream,
                           part, fin, nchunk);
    }
    hipLaunchKernelGGL(attn_out_kernel, dim3(512), dim3(256), 0, stream,
                       Q, fin, outp);
}